// Round 17
// baseline (931.397 us; speedup 1.0000x reference)
//
#include <hip/hip_runtime.h>
#include <hip/hip_bf16.h>

#define BATCH 16
#define CH 256
#define HH 128
#define WW 128
#define HWSZ (HH * WW)
#define NHEAD 8
#define DHEAD 32
#define PW 132       // padded spatial width  (2 halo each side)
#define PPIX (132 * 132)
#define ROWS 264     // lB row stride in shorts
#define ASTR 40      // lA row stride in shorts

typedef __attribute__((ext_vector_type(8))) short bf16x8;
typedef __attribute__((ext_vector_type(4))) float f32x4;
typedef _Float16 h2v __attribute__((ext_vector_type(2)));

__device__ __forceinline__ unsigned short f2h(float f) {
    _Float16 h = (_Float16)f;
    return __builtin_bit_cast(unsigned short, h);
}
// packed f32x2 -> bf16x2 in one u32 (v_cvt_pk_bf16_f32 on gfx950)
__device__ __forceinline__ unsigned pkbf(float a, float b) {
    __hip_bfloat162_raw r = __hip_bfloat162_raw(__float22bfloat162_rn(make_float2(a, b)));
    return (unsigned)r.x | ((unsigned)r.y << 16);
}
// lB chunk swizzle: involution, applied on BOTH write and read sides
__device__ __forceinline__ int swzc(int row, int chunk) { return chunk ^ ((row >> 2) & 7); }

#if __has_builtin(__builtin_amdgcn_fdot2)
#define DOT2(a, b, c) __builtin_amdgcn_fdot2((a), (b), (c), false)
#else
#define DOT2(a, b, c) ((c) + (float)(a)[0] * (float)(b)[0] + (float)(a)[1] * (float)(b)[1])
#endif

// ---------------------------------------------------------------------------
// Kernel Z: zero the spatial border of padded K/V buffers (1040 px per b,h).
// ---------------------------------------------------------------------------
__global__ __launch_bounds__(256)
void zpad_kernel(unsigned short* __restrict__ kpad, unsigned short* __restrict__ vpad)
{
    int bid = blockIdx.x;  // 0..255 : (bh, tensor)
    unsigned short* dst = ((bid & 1) ? vpad : kpad) + (size_t)(bid >> 1) * PPIX * DHEAD;
    const uint4 z = {0u, 0u, 0u, 0u};
    for (int i = threadIdx.x; i < 1040; i += 256) {
        int row, col;
        if (i < 264)      { row = i / 132; col = i - row * 132; }
        else if (i < 528) { int j = i - 264; int r = j / 132; row = 130 + r; col = j - r * 132; }
        else              { int j = i - 528; row = 2 + (j >> 2); int c = j & 3; col = (c < 2) ? c : (128 + c); }
        uint4* p = reinterpret_cast<uint4*>(dst + (size_t)(row * PW + col) * DHEAD);
        p[0] = z; p[1] = z; p[2] = z; p[3] = z;
    }
}

// ---------------------------------------------------------------------------
// Kernel 0: convert wq|wk|wv|wfc fp32 -> bf16, stashed in d_ws tail.
// ---------------------------------------------------------------------------
__global__ __launch_bounds__(256)
void prep_kernel(const float* __restrict__ wq, const float* __restrict__ wk,
                 const float* __restrict__ wv, const float* __restrict__ wfc,
                 unsigned short* __restrict__ wb)
{
    const float* src = (blockIdx.y == 0) ? wq : (blockIdx.y == 1) ? wk
                     : (blockIdx.y == 2) ? wv : wfc;
    unsigned short* dst = wb + blockIdx.y * 65536;
    int e = (blockIdx.x * 256 + threadIdx.x) * 8;
    const float4* s = reinterpret_cast<const float4*>(src + e);
    float4 a = s[0], c = s[1];
    uint4 u;
    u.x = pkbf(a.x, a.y); u.y = pkbf(a.z, a.w);
    u.z = pkbf(c.x, c.y); u.w = pkbf(c.z, c.w);
    *reinterpret_cast<uint4*>(dst + e) = u;
}

// ---------------------------------------------------------------------------
// Kernel 1: projections, PERSISTENT-WITHIN-Z (R16-proven, unchanged).
// ---------------------------------------------------------------------------
__global__ __launch_bounds__(512)
void proj_kernel(const float* __restrict__ q, const float* __restrict__ k,
                 const float* __restrict__ v, const unsigned short* __restrict__ wb,
                 unsigned short* __restrict__ qh, unsigned short* __restrict__ kpad,
                 unsigned short* __restrict__ vpad)
{
    __shared__ __align__(16) unsigned short lB[2][64 * ROWS];   // 67.6 KB

    const int t = threadIdx.x;
    const int z = blockIdx.y;
    const int b = blockIdx.x >> 4;
    const int pt0 = (blockIdx.x & 15) * 16;

    const float* X; unsigned short* Y;
    if (z == 0)      { X = q; Y = qh; }
    else if (z == 1) { X = k; Y = kpad; }
    else             { X = v; Y = vpad; }
    const unsigned short* Wb = wb + z * 65536;
    X += (size_t)b * CH * HWSZ;
    const size_t pixstride = (z == 0) ? (size_t)HWSZ : (size_t)PPIX;
    Y += (size_t)b * NHEAD * pixstride * DHEAD;

    const int lane = t & 63;
    const int wid  = t >> 6;
    const int lrow = lane & 15;
    const int lkg  = lane >> 4;
    const int pxq  = t & 15;
    const int oct  = t >> 4;

    const float* xcol = X + (size_t)(oct * 8) * HWSZ + pxq * 4;

    float4 f[8];
    {
        const float* xb = xcol + pt0 * 64;
#pragma unroll
        for (int i = 0; i < 8; ++i) f[i] = *reinterpret_cast<const float4*>(xb + (size_t)i * HWSZ);
    }
    bf16x8 af[2][8];
#pragma unroll
    for (int m = 0; m < 2; ++m)
#pragma unroll
        for (int ks = 0; ks < 8; ++ks)
            af[m][ks] = *reinterpret_cast<const bf16x8*>(
                Wb + (wid * 32 + m * 16 + lrow) * 256 + ks * 32 + lkg * 8);

#define PACK_LB(BUF) do { \
        uint4 u_; int row_; \
        row_ = pxq * 4 + 0; \
        u_.x = pkbf(f[0].x, f[1].x); u_.y = pkbf(f[2].x, f[3].x); \
        u_.z = pkbf(f[4].x, f[5].x); u_.w = pkbf(f[6].x, f[7].x); \
        *reinterpret_cast<uint4*>(&lB[BUF][row_ * ROWS + swzc(row_, oct) * 8]) = u_; \
        row_ = pxq * 4 + 1; \
        u_.x = pkbf(f[0].y, f[1].y); u_.y = pkbf(f[2].y, f[3].y); \
        u_.z = pkbf(f[4].y, f[5].y); u_.w = pkbf(f[6].y, f[7].y); \
        *reinterpret_cast<uint4*>(&lB[BUF][row_ * ROWS + swzc(row_, oct) * 8]) = u_; \
        row_ = pxq * 4 + 2; \
        u_.x = pkbf(f[0].z, f[1].z); u_.y = pkbf(f[2].z, f[3].z); \
        u_.z = pkbf(f[4].z, f[5].z); u_.w = pkbf(f[6].z, f[7].z); \
        *reinterpret_cast<uint4*>(&lB[BUF][row_ * ROWS + swzc(row_, oct) * 8]) = u_; \
        row_ = pxq * 4 + 3; \
        u_.x = pkbf(f[0].w, f[1].w); u_.y = pkbf(f[2].w, f[3].w); \
        u_.z = pkbf(f[4].w, f[5].w); u_.w = pkbf(f[6].w, f[7].w); \
        *reinterpret_cast<uint4*>(&lB[BUF][row_ * ROWS + swzc(row_, oct) * 8]) = u_; \
    } while (0)

    PACK_LB(0);
    __syncthreads();
    {
        const float* xb = xcol + (pt0 + 1) * 64;
#pragma unroll
        for (int i = 0; i < 8; ++i) f[i] = *reinterpret_cast<const float4*>(xb + (size_t)i * HWSZ);
    }

    for (int it = 0; it < 16; ++it) {
        f32x4 acc[2][4];
        const f32x4 zero = {0.f, 0.f, 0.f, 0.f};
#pragma unroll
        for (int m = 0; m < 2; ++m)
#pragma unroll
            for (int n = 0; n < 4; ++n) acc[m][n] = zero;

#pragma unroll
        for (int ks = 0; ks < 8; ++ks) {
            bf16x8 bfv[4];
#pragma unroll
            for (int n = 0; n < 4; ++n) {
                int row = n * 16 + lrow;
                bfv[n] = *reinterpret_cast<const bf16x8*>(&lB[it & 1][row * ROWS + swzc(row, ks * 4 + lkg) * 8]);
            }
#pragma unroll
            for (int m = 0; m < 2; ++m)
#pragma unroll
                for (int n = 0; n < 4; ++n)
                    acc[m][n] = __builtin_amdgcn_mfma_f32_16x16x32_bf16(af[m][ks], bfv[n], acc[m][n], 0, 0, 0);
        }

        {
            const int p0 = (pt0 + it) * 64;
            const int lr = lane >> 4, lc = lane & 15;
#pragma unroll
            for (int m = 0; m < 2; ++m)
#pragma unroll
                for (int n = 0; n < 4; ++n) {
                    int d0 = m * 16 + lr * 4;
                    int p = p0 + n * 16 + lc;
                    ushort4 pk;
                    pk.x = f2h(acc[m][n][0]); pk.y = f2h(acc[m][n][1]);
                    pk.z = f2h(acc[m][n][2]); pk.w = f2h(acc[m][n][3]);
                    size_t pix;
                    if (z == 0) pix = (size_t)wid * HWSZ + p;
                    else { int row = p >> 7, col = p & 127; pix = (size_t)wid * PPIX + (size_t)(row + 2) * PW + (col + 2); }
                    *reinterpret_cast<ushort4*>(&Y[pix * DHEAD + d0]) = pk;
                }
        }

        if (it + 1 < 16) {
            PACK_LB((it + 1) & 1);
            __syncthreads();
            if (it + 2 < 16) {
                const float* xb = xcol + (pt0 + it + 2) * 64;
#pragma unroll
                for (int i = 0; i < 8; ++i) f[i] = *reinterpret_cast<const float4*>(xb + (size_t)i * HWSZ);
            }
        }
    }
#undef PACK_LB
}

// ---------------------------------------------------------------------------
// Kernel 2: FUSED attn + fc + residual + LayerNorm.
// Block = (batch, 8x16-px tile), 512 threads: px = t>>2, qc = t&3.
// Phase 1: 5x5 window attention per head (h=0..7), result kept in regs
// (ah[8] = full 256-ch pixel vector spread over 4 qc-threads).
// Phase 2/3 (x2 px-halves of 64): dump ah -> swizzled lB panel, then the
// R15 fcln GEMM (lA dbuf) + residual + LN + store. ob traffic eliminated.
// ---------------------------------------------------------------------------
__global__ __launch_bounds__(512)
void attn_fcln_kernel(const unsigned short* __restrict__ qh,
                      const unsigned short* __restrict__ kpad,
                      const unsigned short* __restrict__ vpad,
                      const unsigned short* __restrict__ wfcb,
                      const float* __restrict__ qres, const float* __restrict__ lnw,
                      const float* __restrict__ lnb, float* __restrict__ out)
{
    __shared__ __align__(16) unsigned short lB[64 * ROWS];     // 33 KB
    __shared__ __align__(16) unsigned short lA[2][256 * ASTR]; // 40 KB
    __shared__ float lsum[8][64];
    __shared__ float lssq[8][64];

    const int t = threadIdx.x;
    // XCD swizzle over flat 2048 grid (2048 % 8 == 0 -> bijective)
    const int flat = (blockIdx.x & 7) * 256 + (blockIdx.x >> 3);
    const int b = flat >> 7;           // batch
    const int tile = flat & 127;       // 8x16-px tile
    const int x0 = (tile & 7) * 16, y0 = (tile >> 3) * 8;

    const int px = t >> 2;             // 0..127 local pixel
    const int qc = t & 3;              // 16B quarter
    const int gx = x0 + (px & 15), gy = y0 + (px >> 4);

    // ================= Phase 1: attention, all 8 heads =================
    uint4 ah[8];
#pragma unroll
    for (int h = 0; h < NHEAD; ++h) {
        const size_t plane = (size_t)(b * NHEAD + h);
        const unsigned short* qp = qh + (plane * HWSZ + gy * WW + gx) * DHEAD + qc * 8;
        const unsigned short* kb = kpad + plane * PPIX * DHEAD + qc * 8;
        const unsigned short* vb = vpad + plane * PPIX * DHEAD + qc * 8;

        union { uint4 u; h2v h2[4]; } Q;
        Q.u = *reinterpret_cast<const uint4*>(qp);

        float ew[25];
#pragma unroll
        for (int wy = 0; wy < 5; ++wy) {
            const unsigned short* krow = kb + (size_t)((gy + wy) * PW + gx) * DHEAD;
#pragma unroll
            for (int wx = 0; wx < 5; ++wx) {
                union { uint4 u; h2v h2[4]; } K;
                K.u = *reinterpret_cast<const uint4*>(krow + wx * DHEAD);
                float s = 0.f;
#pragma unroll
                for (int j = 0; j < 4; ++j)
                    s = DOT2(Q.h2[j], K.h2[j], s);
                s += __shfl_xor(s, 1);
                s += __shfl_xor(s, 2);
                ew[wy * 5 + wx] = __expf(fmaxf(s, 0.f) * 0.17677669529663687f);
            }
        }

        float sum = 0.f;
#pragma unroll
        for (int i = 0; i < 25; ++i) sum += ew[i];
        const float inv = 1.f / sum;

        union { uint4 u; h2v h2[4]; } A;
        const h2v hz = {(_Float16)0.f, (_Float16)0.f};
#pragma unroll
        for (int j = 0; j < 4; ++j) A.h2[j] = hz;

#pragma unroll
        for (int wy = 0; wy < 5; ++wy) {
            const unsigned short* vrow = vb + (size_t)((gy + wy) * PW + gx) * DHEAD;
#pragma unroll
            for (int wx = 0; wx < 5; ++wx) {
                _Float16 wh = (_Float16)(ew[wy * 5 + wx] * inv);
                h2v w2 = {wh, wh};
                union { uint4 u; h2v h2[4]; } V;
                V.u = *reinterpret_cast<const uint4*>(vrow + wx * DHEAD);
#pragma unroll
                for (int j = 0; j < 4; ++j)
                    A.h2[j] += w2 * V.h2[j];
            }
        }

        uint4 o;
        o.x = pkbf((float)A.h2[0][0], (float)A.h2[0][1]);
        o.y = pkbf((float)A.h2[1][0], (float)A.h2[1][1]);
        o.z = pkbf((float)A.h2[2][0], (float)A.h2[2][1]);
        o.w = pkbf((float)A.h2[3][0], (float)A.h2[3][1]);
        ah[h] = o;
    }

    // ============== Phase 2/3: fc GEMM + residual + LN, two 64px halves ====
    const int lane = t & 63;
    const int wid  = t >> 6;
    const int lrow = lane & 15;
    const int lkg  = lane >> 4;
    const int ao0 = t >> 1, ak0 = (t & 1) * 2;
    const float* qb = qres + (size_t)b * CH * HWSZ;
    float* opb = out + (size_t)b * CH * HWSZ;

    for (int g = 0; g < 2; ++g) {
        __syncthreads();   // lB/lA safe to overwrite (prev group fully done)

        // write this half's attn results into lB (rows 0..63 = local px)
        if ((px >> 6) == g) {
            int r = px & 63;
#pragma unroll
            for (int h = 0; h < NHEAD; ++h)
                *reinterpret_cast<uint4*>(&lB[r * ROWS + swzc(r, h * 4 + qc) * 8]) = ah[h];
        }
        // stage lA[0]
        {
            uint4 w0 = *reinterpret_cast<const uint4*>(wfcb + ao0 * 256 + ak0 * 8);
            uint4 w1 = *reinterpret_cast<const uint4*>(wfcb + ao0 * 256 + ak0 * 8 + 8);
            *reinterpret_cast<uint4*>(&lA[0][ao0 * ASTR + ak0 * 8]) = w0;
            *reinterpret_cast<uint4*>(&lA[0][ao0 * ASTR + ak0 * 8 + 8]) = w1;
        }

        f32x4 acc[2][4];
        const f32x4 zero = {0.f, 0.f, 0.f, 0.f};
#pragma unroll
        for (int m = 0; m < 2; ++m)
#pragma unroll
            for (int n = 0; n < 4; ++n) acc[m][n] = zero;

        __syncthreads();

#pragma unroll
        for (int ks = 0; ks < 8; ++ks) {
            uint4 w0, w1;
            if (ks < 7) {
                w0 = *reinterpret_cast<const uint4*>(wfcb + ao0 * 256 + (ks + 1) * 32 + ak0 * 8);
                w1 = *reinterpret_cast<const uint4*>(wfcb + ao0 * 256 + (ks + 1) * 32 + ak0 * 8 + 8);
            }
            bf16x8 af[2], bfv[4];
#pragma unroll
            for (int m = 0; m < 2; ++m)
                af[m] = *reinterpret_cast<const bf16x8*>(&lA[ks & 1][(wid * 32 + m * 16 + lrow) * ASTR + lkg * 8]);
#pragma unroll
            for (int n = 0; n < 4; ++n) {
                int row = n * 16 + lrow;
                bfv[n] = *reinterpret_cast<const bf16x8*>(&lB[row * ROWS + swzc(row, ks * 4 + lkg) * 8]);
            }
#pragma unroll
            for (int m = 0; m < 2; ++m)
#pragma unroll
                for (int n = 0; n < 4; ++n)
                    acc[m][n] = __builtin_amdgcn_mfma_f32_16x16x32_bf16(af[m], bfv[n], acc[m][n], 0, 0, 0);
            if (ks < 7) {
                *reinterpret_cast<uint4*>(&lA[(ks + 1) & 1][ao0 * ASTR + ak0 * 8]) = w0;
                *reinterpret_cast<uint4*>(&lA[(ks + 1) & 1][ao0 * ASTR + ak0 * 8 + 8]) = w1;
                __syncthreads();
            }
        }

        // residual add (p: local row r = n*16+lc -> global (y0+g*4+n, x0+lc))
        const int lr = lane >> 4, lc = lane & 15;
#pragma unroll
        for (int m = 0; m < 2; ++m)
#pragma unroll
            for (int n = 0; n < 4; ++n) {
                int p = (y0 + g * 4 + n) * WW + x0 + lc;
#pragma unroll
                for (int j = 0; j < 4; ++j) {
                    int o = wid * 32 + m * 16 + lr * 4 + j;
                    acc[m][n][j] += qb[(size_t)o * HWSZ + p];
                }
            }

        float s[4], s2[4];
#pragma unroll
        for (int n = 0; n < 4; ++n) {
            float a = 0.f, c2 = 0.f;
#pragma unroll
            for (int m = 0; m < 2; ++m)
#pragma unroll
                for (int j = 0; j < 4; ++j) {
                    float x = acc[m][n][j];
                    a += x; c2 += x * x;
                }
            a  += __shfl_xor(a, 16);  a  += __shfl_xor(a, 32);
            c2 += __shfl_xor(c2, 16); c2 += __shfl_xor(c2, 32);
            s[n] = a; s2[n] = c2;
        }
        __syncthreads();
        if (lane < 16) {
#pragma unroll
            for (int n = 0; n < 4; ++n) {
                lsum[wid][n * 16 + lane] = s[n];
                lssq[wid][n * 16 + lane] = s2[n];
            }
        }
        __syncthreads();

        float mu[4], rs[4];
#pragma unroll
        for (int n = 0; n < 4; ++n) {
            int pp = n * 16 + lc;
            float ts = 0.f, tq = 0.f;
#pragma unroll
            for (int w = 0; w < 8; ++w) { ts += lsum[w][pp]; tq += lssq[w][pp]; }
            float m_ = ts * (1.f / 256.f);
            float v_ = tq * (1.f / 256.f) - m_ * m_;
            mu[n] = m_;
            rs[n] = rsqrtf(v_ + 1e-6f);
        }

#pragma unroll
        for (int m = 0; m < 2; ++m)
#pragma unroll
            for (int j = 0; j < 4; ++j) {
                int o = wid * 32 + m * 16 + lr * 4 + j;
                float gw = lnw[o], bb = lnb[o];
#pragma unroll
                for (int n = 0; n < 4; ++n) {
                    int p = (y0 + g * 4 + n) * WW + x0 + lc;
                    opb[(size_t)o * HWSZ + p] = (acc[m][n][j] - mu[n]) * rs[n] * gw + bb;
                }
            }
    }
}

extern "C" void kernel_launch(void* const* d_in, const int* in_sizes, int n_in,
                              void* d_out, int out_size, void* d_ws, size_t ws_size,
                              hipStream_t stream) {
    const float* q   = (const float*)d_in[0];
    const float* k   = (const float*)d_in[1];
    const float* v   = (const float*)d_in[2];
    const float* wq  = (const float*)d_in[3];
    const float* wk  = (const float*)d_in[4];
    const float* wv  = (const float*)d_in[5];
    const float* wfc = (const float*)d_in[6];
    const float* lnw = (const float*)d_in[7];
    const float* lnb = (const float*)d_in[8];

    const size_t qsz = (size_t)BATCH * NHEAD * HWSZ * DHEAD;   // 67,108,864
    const size_t psz = (size_t)BATCH * NHEAD * PPIX * DHEAD;   // 71,368,704
    if (ws_size < (qsz + 2 * psz + 4 * 65536) * sizeof(unsigned short)) return;

    unsigned short* qh = (unsigned short*)d_ws;   // q proj (f16)
    unsigned short* kp = qh + qsz;
    unsigned short* vp = kp + psz;
    unsigned short* wb = vp + psz;                // 512KB bf16 weight stash (wq|wk|wv|wfc)

    zpad_kernel<<<256, 256, 0, stream>>>(kp, vp);
    prep_kernel<<<dim3(32, 4), 256, 0, stream>>>(wq, wk, wv, wfc, wb);
    proj_kernel<<<dim3(256, 3), 512, 0, stream>>>(q, k, v, wb, qh, kp, vp);
    attn_fcln_kernel<<<2048, 512, 0, stream>>>(qh, kp, vp, wb + 3 * 65536, q, lnw, lnb, (float*)d_out);
}

// Round 18
// 688.697 us; speedup vs baseline: 1.3524x; 1.3524x over previous
//
#include <hip/hip_runtime.h>
#include <hip/hip_bf16.h>

#define BATCH 16
#define CH 256
#define HH 128
#define WW 128
#define HWSZ (HH * WW)
#define NHEAD 8
#define DHEAD 32
#define PW 132       // padded spatial width  (2 halo each side)
#define PPIX (132 * 132)
#define ROWS 264     // lB row stride in shorts
#define ASTR 40      // lA row stride in shorts (fcln only)

typedef __attribute__((ext_vector_type(8))) short bf16x8;
typedef __attribute__((ext_vector_type(4))) float f32x4;
typedef _Float16 h2v __attribute__((ext_vector_type(2)));

__device__ __forceinline__ unsigned short f2h(float f) {
    _Float16 h = (_Float16)f;
    return __builtin_bit_cast(unsigned short, h);
}
// packed f32x2 -> bf16x2 in one u32 (v_cvt_pk_bf16_f32 on gfx950)
__device__ __forceinline__ unsigned pkbf(float a, float b) {
    __hip_bfloat162_raw r = __hip_bfloat162_raw(__float22bfloat162_rn(make_float2(a, b)));
    return (unsigned)r.x | ((unsigned)r.y << 16);
}
// lB chunk swizzle: involution, applied on BOTH write and read sides
__device__ __forceinline__ int swzc(int row, int chunk) { return chunk ^ ((row >> 2) & 7); }

#if __has_builtin(__builtin_amdgcn_fdot2)
#define DOT2(a, b, c) __builtin_amdgcn_fdot2((a), (b), (c), false)
#else
#define DOT2(a, b, c) ((c) + (float)(a)[0] * (float)(b)[0] + (float)(a)[1] * (float)(b)[1])
#endif

// ---------------------------------------------------------------------------
// Kernel Z: zero the spatial border of padded K/V buffers (1040 px per b,h).
// ---------------------------------------------------------------------------
__global__ __launch_bounds__(256)
void zpad_kernel(unsigned short* __restrict__ kpad, unsigned short* __restrict__ vpad)
{
    int bid = blockIdx.x;  // 0..255 : (bh, tensor)
    unsigned short* dst = ((bid & 1) ? vpad : kpad) + (size_t)(bid >> 1) * PPIX * DHEAD;
    const uint4 z = {0u, 0u, 0u, 0u};
    for (int i = threadIdx.x; i < 1040; i += 256) {
        int row, col;
        if (i < 264)      { row = i / 132; col = i - row * 132; }
        else if (i < 528) { int j = i - 264; int r = j / 132; row = 130 + r; col = j - r * 132; }
        else              { int j = i - 528; row = 2 + (j >> 2); int c = j & 3; col = (c < 2) ? c : (128 + c); }
        uint4* p = reinterpret_cast<uint4*>(dst + (size_t)(row * PW + col) * DHEAD);
        p[0] = z; p[1] = z; p[2] = z; p[3] = z;
    }
}

// ---------------------------------------------------------------------------
// Kernel 0: convert wq|wk|wv|wfc fp32 -> bf16, stashed in d_ws tail.
// ---------------------------------------------------------------------------
__global__ __launch_bounds__(256)
void prep_kernel(const float* __restrict__ wq, const float* __restrict__ wk,
                 const float* __restrict__ wv, const float* __restrict__ wfc,
                 unsigned short* __restrict__ wb)
{
    const float* src = (blockIdx.y == 0) ? wq : (blockIdx.y == 1) ? wk
                     : (blockIdx.y == 2) ? wv : wfc;
    unsigned short* dst = wb + blockIdx.y * 65536;
    int e = (blockIdx.x * 256 + threadIdx.x) * 8;
    const float4* s = reinterpret_cast<const float4*>(src + e);
    float4 a = s[0], c = s[1];
    uint4 u;
    u.x = pkbf(a.x, a.y); u.y = pkbf(a.z, a.w);
    u.z = pkbf(c.x, c.y); u.w = pkbf(c.z, c.w);
    *reinterpret_cast<uint4*>(dst + e) = u;
}

// ---------------------------------------------------------------------------
// Kernel 1: projections, PERSISTENT-WITHIN-Z (R16-proven, unchanged).
// ---------------------------------------------------------------------------
__global__ __launch_bounds__(512)
void proj_kernel(const float* __restrict__ q, const float* __restrict__ k,
                 const float* __restrict__ v, const unsigned short* __restrict__ wb,
                 unsigned short* __restrict__ qh, unsigned short* __restrict__ kpad,
                 unsigned short* __restrict__ vpad)
{
    __shared__ __align__(16) unsigned short lB[2][64 * ROWS];   // 67.6 KB

    const int t = threadIdx.x;
    const int z = blockIdx.y;
    const int b = blockIdx.x >> 4;
    const int pt0 = (blockIdx.x & 15) * 16;

    const float* X; unsigned short* Y;
    if (z == 0)      { X = q; Y = qh; }
    else if (z == 1) { X = k; Y = kpad; }
    else             { X = v; Y = vpad; }
    const unsigned short* Wb = wb + z * 65536;
    X += (size_t)b * CH * HWSZ;
    const size_t pixstride = (z == 0) ? (size_t)HWSZ : (size_t)PPIX;
    Y += (size_t)b * NHEAD * pixstride * DHEAD;

    const int lane = t & 63;
    const int wid  = t >> 6;
    const int lrow = lane & 15;
    const int lkg  = lane >> 4;
    const int pxq  = t & 15;
    const int oct  = t >> 4;

    const float* xcol = X + (size_t)(oct * 8) * HWSZ + pxq * 4;

    float4 f[8];
    {
        const float* xb = xcol + pt0 * 64;
#pragma unroll
        for (int i = 0; i < 8; ++i) f[i] = *reinterpret_cast<const float4*>(xb + (size_t)i * HWSZ);
    }
    bf16x8 af[2][8];
#pragma unroll
    for (int m = 0; m < 2; ++m)
#pragma unroll
        for (int ks = 0; ks < 8; ++ks)
            af[m][ks] = *reinterpret_cast<const bf16x8*>(
                Wb + (wid * 32 + m * 16 + lrow) * 256 + ks * 32 + lkg * 8);

#define PACK_LB(BUF) do { \
        uint4 u_; int row_; \
        row_ = pxq * 4 + 0; \
        u_.x = pkbf(f[0].x, f[1].x); u_.y = pkbf(f[2].x, f[3].x); \
        u_.z = pkbf(f[4].x, f[5].x); u_.w = pkbf(f[6].x, f[7].x); \
        *reinterpret_cast<uint4*>(&lB[BUF][row_ * ROWS + swzc(row_, oct) * 8]) = u_; \
        row_ = pxq * 4 + 1; \
        u_.x = pkbf(f[0].y, f[1].y); u_.y = pkbf(f[2].y, f[3].y); \
        u_.z = pkbf(f[4].y, f[5].y); u_.w = pkbf(f[6].y, f[7].y); \
        *reinterpret_cast<uint4*>(&lB[BUF][row_ * ROWS + swzc(row_, oct) * 8]) = u_; \
        row_ = pxq * 4 + 2; \
        u_.x = pkbf(f[0].z, f[1].z); u_.y = pkbf(f[2].z, f[3].z); \
        u_.z = pkbf(f[4].z, f[5].z); u_.w = pkbf(f[6].z, f[7].z); \
        *reinterpret_cast<uint4*>(&lB[BUF][row_ * ROWS + swzc(row_, oct) * 8]) = u_; \
        row_ = pxq * 4 + 3; \
        u_.x = pkbf(f[0].w, f[1].w); u_.y = pkbf(f[2].w, f[3].w); \
        u_.z = pkbf(f[4].w, f[5].w); u_.w = pkbf(f[6].w, f[7].w); \
        *reinterpret_cast<uint4*>(&lB[BUF][row_ * ROWS + swzc(row_, oct) * 8]) = u_; \
    } while (0)

    PACK_LB(0);
    __syncthreads();
    {
        const float* xb = xcol + (pt0 + 1) * 64;
#pragma unroll
        for (int i = 0; i < 8; ++i) f[i] = *reinterpret_cast<const float4*>(xb + (size_t)i * HWSZ);
    }

    for (int it = 0; it < 16; ++it) {
        f32x4 acc[2][4];
        const f32x4 zero = {0.f, 0.f, 0.f, 0.f};
#pragma unroll
        for (int m = 0; m < 2; ++m)
#pragma unroll
            for (int n = 0; n < 4; ++n) acc[m][n] = zero;

#pragma unroll
        for (int ks = 0; ks < 8; ++ks) {
            bf16x8 bfv[4];
#pragma unroll
            for (int n = 0; n < 4; ++n) {
                int row = n * 16 + lrow;
                bfv[n] = *reinterpret_cast<const bf16x8*>(&lB[it & 1][row * ROWS + swzc(row, ks * 4 + lkg) * 8]);
            }
#pragma unroll
            for (int m = 0; m < 2; ++m)
#pragma unroll
                for (int n = 0; n < 4; ++n)
                    acc[m][n] = __builtin_amdgcn_mfma_f32_16x16x32_bf16(af[m][ks], bfv[n], acc[m][n], 0, 0, 0);
        }

        {
            const int p0 = (pt0 + it) * 64;
            const int lr = lane >> 4, lc = lane & 15;
#pragma unroll
            for (int m = 0; m < 2; ++m)
#pragma unroll
                for (int n = 0; n < 4; ++n) {
                    int d0 = m * 16 + lr * 4;
                    int p = p0 + n * 16 + lc;
                    ushort4 pk;
                    pk.x = f2h(acc[m][n][0]); pk.y = f2h(acc[m][n][1]);
                    pk.z = f2h(acc[m][n][2]); pk.w = f2h(acc[m][n][3]);
                    size_t pix;
                    if (z == 0) pix = (size_t)wid * HWSZ + p;
                    else { int row = p >> 7, col = p & 127; pix = (size_t)wid * PPIX + (size_t)(row + 2) * PW + (col + 2); }
                    *reinterpret_cast<ushort4*>(&Y[pix * DHEAD + d0]) = pk;
                }
        }

        if (it + 1 < 16) {
            PACK_LB((it + 1) & 1);
            __syncthreads();
            if (it + 2 < 16) {
                const float* xb = xcol + (pt0 + it + 2) * 64;
#pragma unroll
                for (int i = 0; i < 8; ++i) f[i] = *reinterpret_cast<const float4*>(xb + (size_t)i * HWSZ);
            }
        }
    }
#undef PACK_LB
}

// ---------------------------------------------------------------------------
// Kernel 2: local 5x5 attention — 4 lanes per pixel, contiguous 1KB/wave.
// R18 change: corr phase batched — all 25 dot-partials computed first
// (K-loads free to pipeline), then shfl/exp pass. Output bf16 in place.
// ---------------------------------------------------------------------------
__global__ __launch_bounds__(1024)
void attn_kernel(unsigned short* __restrict__ qh,
                 const unsigned short* __restrict__ kpad,
                 const unsigned short* __restrict__ vpad)
{
    const int t = threadIdx.x;
    const int swz = (blockIdx.x & 7) * 1024 + (blockIdx.x >> 3);
    const int bh = swz >> 6;
    const int tile = swz & 63;
    const int x0 = (tile & 7) * 16, y0 = (tile >> 3) * 16;
    const int qc = t & 3;
    const int px = (t >> 2) & 15;
    const int py = t >> 6;
    const int gx = x0 + px, gy = y0 + py;

    unsigned short* qp = qh + ((size_t)bh * HWSZ + gy * WW + gx) * DHEAD + qc * 8;
    const unsigned short* kb = kpad + (size_t)bh * PPIX * DHEAD + qc * 8;
    const unsigned short* vb = vpad + (size_t)bh * PPIX * DHEAD + qc * 8;

    union { uint4 u; h2v h2[4]; } Q;
    Q.u = *reinterpret_cast<const uint4*>(qp);

    // pass 1: all 25 quarter-dot partials (no cross-lane ops -> loads pipeline)
    float sp[25];
#pragma unroll
    for (int wy = 0; wy < 5; ++wy) {
        const unsigned short* krow = kb + (size_t)((gy + wy) * PW + gx) * DHEAD;
#pragma unroll
        for (int wx = 0; wx < 5; ++wx) {
            union { uint4 u; h2v h2[4]; } K;
            K.u = *reinterpret_cast<const uint4*>(krow + wx * DHEAD);
            float s = 0.f;
#pragma unroll
            for (int j = 0; j < 4; ++j)
                s = DOT2(Q.h2[j], K.h2[j], s);
            sp[wy * 5 + wx] = s;
        }
    }
    // pass 2: cross-lane combine + exp
    float ew[25];
#pragma unroll
    for (int i = 0; i < 25; ++i) {
        float s = sp[i];
        s += __shfl_xor(s, 1);
        s += __shfl_xor(s, 2);
        ew[i] = __expf(fmaxf(s, 0.f) * 0.17677669529663687f);
    }

    float sum = 0.f;
#pragma unroll
    for (int i = 0; i < 25; ++i) sum += ew[i];
    const float inv = 1.f / sum;

    union { uint4 u; h2v h2[4]; } A;
    const h2v hz = {(_Float16)0.f, (_Float16)0.f};
#pragma unroll
    for (int j = 0; j < 4; ++j) A.h2[j] = hz;

#pragma unroll
    for (int wy = 0; wy < 5; ++wy) {
        const unsigned short* vrow = vb + (size_t)((gy + wy) * PW + gx) * DHEAD;
#pragma unroll
        for (int wx = 0; wx < 5; ++wx) {
            _Float16 wh = (_Float16)(ew[wy * 5 + wx] * inv);
            h2v w2 = {wh, wh};
            union { uint4 u; h2v h2[4]; } V;
            V.u = *reinterpret_cast<const uint4*>(vrow + wx * DHEAD);
#pragma unroll
            for (int j = 0; j < 4; ++j)
                A.h2[j] += w2 * V.h2[j];
        }
    }

    uint4 o;
    o.x = pkbf((float)A.h2[0][0], (float)A.h2[0][1]);
    o.y = pkbf((float)A.h2[1][0], (float)A.h2[1][1]);
    o.z = pkbf((float)A.h2[2][0], (float)A.h2[2][1]);
    o.w = pkbf((float)A.h2[3][0], (float)A.h2[3][1]);
    *reinterpret_cast<uint4*>(qp) = o;
}

// ---------------------------------------------------------------------------
// Kernel 3: o = wfc @ attn_out + residual, LayerNorm. R15/R16-proven
// structure (lA dbuf + lB swizzled full panel), unchanged.
// ---------------------------------------------------------------------------
__global__ __launch_bounds__(512)
void fcln_kernel(const unsigned short* __restrict__ ob, const unsigned short* __restrict__ wfcb,
                 const float* __restrict__ qres, const float* __restrict__ lnw,
                 const float* __restrict__ lnb, float* __restrict__ out)
{
    __shared__ __align__(16) unsigned short lB[64 * ROWS];     // 33 KB
    __shared__ __align__(16) unsigned short lA[2][256 * ASTR]; // 40 KB
    __shared__ float lsum[8][64];
    __shared__ float lssq[8][64];

    const int t = threadIdx.x;
    const int b = blockIdx.y;
    const int p0 = blockIdx.x * 64;

    const int lane = t & 63;
    const int wid  = t >> 6;
    const int lrow = lane & 15;
    const int lkg  = lane >> 4;
    const int ao0 = t >> 1, ak0 = (t & 1) * 2;

    // ---- stage lB: 4 x uint4 per thread (contiguous 1KB/wave), swizzled
#pragma unroll
    for (int r = 0; r < 4; ++r) {
        int idx = r * 512 + t;
        int h = idx >> 8;
        int rem = idx & 255;
        int px = rem >> 2, qc = rem & 3;
        uint4 bv = *reinterpret_cast<const uint4*>(
            ob + ((size_t)(b * NHEAD + h) * HWSZ + p0 + px) * DHEAD + qc * 8);
        *reinterpret_cast<uint4*>(&lB[px * ROWS + swzc(px, h * 4 + qc) * 8]) = bv;
    }
    // ---- stage lA[0] ----
    {
        uint4 w0 = *reinterpret_cast<const uint4*>(wfcb + ao0 * 256 + ak0 * 8);
        uint4 w1 = *reinterpret_cast<const uint4*>(wfcb + ao0 * 256 + ak0 * 8 + 8);
        *reinterpret_cast<uint4*>(&lA[0][ao0 * ASTR + ak0 * 8]) = w0;
        *reinterpret_cast<uint4*>(&lA[0][ao0 * ASTR + ak0 * 8 + 8]) = w1;
    }

    f32x4 acc[2][4];
    const f32x4 zero = {0.f, 0.f, 0.f, 0.f};
#pragma unroll
    for (int m = 0; m < 2; ++m)
#pragma unroll
        for (int n = 0; n < 4; ++n) acc[m][n] = zero;

    __syncthreads();

#pragma unroll
    for (int ks = 0; ks < 8; ++ks) {
        uint4 w0, w1;
        if (ks < 7) {
            w0 = *reinterpret_cast<const uint4*>(wfcb + ao0 * 256 + (ks + 1) * 32 + ak0 * 8);
            w1 = *reinterpret_cast<const uint4*>(wfcb + ao0 * 256 + (ks + 1) * 32 + ak0 * 8 + 8);
        }
        bf16x8 af[2], bfv[4];
#pragma unroll
        for (int m = 0; m < 2; ++m)
            af[m] = *reinterpret_cast<const bf16x8*>(&lA[ks & 1][(wid * 32 + m * 16 + lrow) * ASTR + lkg * 8]);
#pragma unroll
        for (int n = 0; n < 4; ++n) {
            int row = n * 16 + lrow;
            bfv[n] = *reinterpret_cast<const bf16x8*>(&lB[row * ROWS + swzc(row, ks * 4 + lkg) * 8]);
        }
#pragma unroll
        for (int m = 0; m < 2; ++m)
#pragma unroll
            for (int n = 0; n < 4; ++n)
                acc[m][n] = __builtin_amdgcn_mfma_f32_16x16x32_bf16(af[m], bfv[n], acc[m][n], 0, 0, 0);
        if (ks < 7) {
            *reinterpret_cast<uint4*>(&lA[(ks + 1) & 1][ao0 * ASTR + ak0 * 8]) = w0;
            *reinterpret_cast<uint4*>(&lA[(ks + 1) & 1][ao0 * ASTR + ak0 * 8 + 8]) = w1;
            __syncthreads();
        }
    }

    const int lr = lane >> 4, lc = lane & 15;
    const float* qb = qres + (size_t)b * CH * HWSZ;
#pragma unroll
    for (int m = 0; m < 2; ++m)
#pragma unroll
        for (int n = 0; n < 4; ++n)
#pragma unroll
            for (int j = 0; j < 4; ++j) {
                int o = wid * 32 + m * 16 + lr * 4 + j;
                int p = p0 + n * 16 + lc;
                acc[m][n][j] += qb[(size_t)o * HWSZ + p];
            }

    float s[4], s2[4];
#pragma unroll
    for (int n = 0; n < 4; ++n) {
        float a = 0.f, c2 = 0.f;
#pragma unroll
        for (int m = 0; m < 2; ++m)
#pragma unroll
            for (int j = 0; j < 4; ++j) {
                float x = acc[m][n][j];
                a += x; c2 += x * x;
            }
        a  += __shfl_xor(a, 16);  a  += __shfl_xor(a, 32);
        c2 += __shfl_xor(c2, 16); c2 += __shfl_xor(c2, 32);
        s[n] = a; s2[n] = c2;
    }
    __syncthreads();
    if (lane < 16) {
#pragma unroll
        for (int n = 0; n < 4; ++n) {
            lsum[wid][n * 16 + lane] = s[n];
            lssq[wid][n * 16 + lane] = s2[n];
        }
    }
    __syncthreads();

    float mu[4], rs[4];
#pragma unroll
    for (int n = 0; n < 4; ++n) {
        int p = n * 16 + lc;
        float ts = 0.f, tq = 0.f;
#pragma unroll
        for (int w = 0; w < 8; ++w) { ts += lsum[w][p]; tq += lssq[w][p]; }
        float m_ = ts * (1.f / 256.f);
        float v_ = tq * (1.f / 256.f) - m_ * m_;
        mu[n] = m_;
        rs[n] = rsqrtf(v_ + 1e-6f);
    }

    float* op = out + (size_t)b * CH * HWSZ;
#pragma unroll
    for (int m = 0; m < 2; ++m)
#pragma unroll
        for (int j = 0; j < 4; ++j) {
            int o = wid * 32 + m * 16 + lr * 4 + j;
            float g = lnw[o], bb = lnb[o];
#pragma unroll
            for (int n = 0; n < 4; ++n) {
                int p = p0 + n * 16 + lc;
                op[(size_t)o * HWSZ + p] = (acc[m][n][j] - mu[n]) * rs[n] * g + bb;
            }
        }
}

extern "C" void kernel_launch(void* const* d_in, const int* in_sizes, int n_in,
                              void* d_out, int out_size, void* d_ws, size_t ws_size,
                              hipStream_t stream) {
    const float* q   = (const float*)d_in[0];
    const float* k   = (const float*)d_in[1];
    const float* v   = (const float*)d_in[2];
    const float* wq  = (const float*)d_in[3];
    const float* wk  = (const float*)d_in[4];
    const float* wv  = (const float*)d_in[5];
    const float* wfc = (const float*)d_in[6];
    const float* lnw = (const float*)d_in[7];
    const float* lnb = (const float*)d_in[8];

    const size_t qsz = (size_t)BATCH * NHEAD * HWSZ * DHEAD;   // 67,108,864
    const size_t psz = (size_t)BATCH * NHEAD * PPIX * DHEAD;   // 71,368,704
    if (ws_size < (qsz + 2 * psz + 4 * 65536) * sizeof(unsigned short)) return;

    unsigned short* qh = (unsigned short*)d_ws;   // q proj (f16), then attn output (bf16, in place)
    unsigned short* kp = qh + qsz;
    unsigned short* vp = kp + psz;
    unsigned short* wb = vp + psz;                // 512KB bf16 weight stash (wq|wk|wv|wfc)

    zpad_kernel<<<256, 256, 0, stream>>>(kp, vp);
    prep_kernel<<<dim3(32, 4), 256, 0, stream>>>(wq, wk, wv, wfc, wb);
    proj_kernel<<<dim3(256, 3), 512, 0, stream>>>(q, k, v, wb, qh, kp, vp);
    attn_kernel<<<8192, 1024, 0, stream>>>(qh, kp, vp);
    fcln_kernel<<<dim3(HWSZ / 64, BATCH), 512, 0, stream>>>(qh, wb + 3 * 65536, q, lnw, lnb, (float*)d_out);
}